// Round 5
// baseline (389.012 us; speedup 1.0000x reference)
//
#include <hip/hip_runtime.h>

#define IN_DIM  4096
#define OUT_DIM 1024
#define NN      4096
#define MM      8192
#define NSAMP   10

typedef __bf16 bf16x8 __attribute__((ext_vector_type(8)));
typedef float  fx4    __attribute__((ext_vector_type(4)));

__device__ __forceinline__ ushort f2bf(float f) {
    union { float f; unsigned u; } v; v.f = f;
    unsigned u = v.u;
    return (ushort)((u + 0x7FFFu + ((u >> 16) & 1u)) >> 16);
}
__device__ __forceinline__ float bf2f(ushort u) {
    union { unsigned u; float f; } v; v.u = ((unsigned)u) << 16;
    return v.f;
}

// async global->LDS, 16B per lane; LDS dest = wave-uniform base + lane*16
#define GLDS(g, l) __builtin_amdgcn_global_load_lds(                           \
    (const __attribute__((address_space(1))) unsigned*)(g),                    \
    (__attribute__((address_space(3))) unsigned*)(l), 16, 0, 0)

// ---------------------------------------------------------------------------
// K1: v1[k] = sum_o a1[o]*W[o,k];  v2[k] = sum_o a2[o]*W[o,k]
//     + fused: Wbf = bf16(W).  float4-vectorized along k (row-contiguous).
// grid (4, 64): x = 1024-k-float4 tile, y = o-slice of 16; atomicAdd partials.
// ---------------------------------------------------------------------------
__global__ __launch_bounds__(256) void k_attvec(const float* __restrict__ W,
                                                const float* __restrict__ att,
                                                float* __restrict__ v1,
                                                float* __restrict__ v2,
                                                ushort* __restrict__ Wbf) {
    int k4 = blockIdx.x * 256 + threadIdx.x;    // float4 column index
    int o0 = blockIdx.y * 16;
    const float4* W4 = reinterpret_cast<const float4*>(W);
    ushort4* Wb4 = reinterpret_cast<ushort4*>(Wbf);
    float4 s1 = {0.f, 0.f, 0.f, 0.f}, s2 = {0.f, 0.f, 0.f, 0.f};
    for (int o = o0; o < o0 + 16; ++o) {
        float4 w = W4[(size_t)o * (IN_DIM / 4) + k4];
        ushort4 ub;
        ub.x = f2bf(w.x); ub.y = f2bf(w.y); ub.z = f2bf(w.z); ub.w = f2bf(w.w);
        Wb4[(size_t)o * (IN_DIM / 4) + k4] = ub;
        float a1 = att[o], a2 = att[OUT_DIM + o];
        s1.x += a1 * w.x; s1.y += a1 * w.y; s1.z += a1 * w.z; s1.w += a1 * w.w;
        s2.x += a2 * w.x; s2.y += a2 * w.y; s2.z += a2 * w.z; s2.w += a2 * w.w;
    }
    int k = k4 * 4;
    atomicAdd(&v1[k],     s1.x); atomicAdd(&v1[k + 1], s1.y);
    atomicAdd(&v1[k + 2], s1.z); atomicAdd(&v1[k + 3], s1.w);
    atomicAdd(&v2[k],     s2.x); atomicAdd(&v2[k + 1], s2.y);
    atomicAdd(&v2[k + 2], s2.z); atomicAdd(&v2[k + 3], s2.w);
}

// ---------------------------------------------------------------------------
// K2 (fused): one block per row over NN + MM rows.
//   row < NN:  nalpha[row] = node_f[row,:] . v1
//   row >= NN: j = row-NN;  nbeta[j] = neigh_f[j,:] . v2  AND Abf[j,:] = bf16
// ---------------------------------------------------------------------------
__global__ __launch_bounds__(256) void k_rows(const float* __restrict__ node_f,
                                              const float* __restrict__ neigh_f,
                                              const float* __restrict__ v1,
                                              const float* __restrict__ v2,
                                              float* __restrict__ nalpha,
                                              float* __restrict__ nbeta,
                                              ushort* __restrict__ Abf) {
    int row = blockIdx.x;
    float s = 0.f;
    if (row < NN) {
        const float4* xr = reinterpret_cast<const float4*>(node_f + (size_t)row * IN_DIM);
        const float4* vr = reinterpret_cast<const float4*>(v1);
        for (int i = threadIdx.x; i < IN_DIM / 4; i += 256) {
            float4 a = xr[i], b = vr[i];
            s += a.x * b.x + a.y * b.y + a.z * b.z + a.w * b.w;
        }
    } else {
        int j = row - NN;
        const float4* xr = reinterpret_cast<const float4*>(neigh_f + (size_t)j * IN_DIM);
        const float4* vr = reinterpret_cast<const float4*>(v2);
        ushort4* yr = reinterpret_cast<ushort4*>(Abf + (size_t)j * IN_DIM);
        for (int i = threadIdx.x; i < IN_DIM / 4; i += 256) {
            float4 a = xr[i], b = vr[i];
            s += a.x * b.x + a.y * b.y + a.z * b.z + a.w * b.w;
            ushort4 o;
            o.x = f2bf(a.x); o.y = f2bf(a.y); o.z = f2bf(a.z); o.w = f2bf(a.w);
            yr[i] = o;
        }
    }
    for (int off = 32; off > 0; off >>= 1) s += __shfl_down(s, off, 64);
    __shared__ float ws[4];
    if ((threadIdx.x & 63) == 0) ws[threadIdx.x >> 6] = s;
    __syncthreads();
    if (threadIdx.x == 0) {
        float t = ws[0] + ws[1] + ws[2] + ws[3];
        if (row < NN) nalpha[row] = t; else nbeta[row - NN] = t;
    }
}

// ---------------------------------------------------------------------------
// K5: split-K x2 GEMM, BK=64 as TWO BK=32 sub-buffers (As[h]/Bs[h] each keep
// the HW-proven packed 64B-row layout; GLDS global addrs are free-form per
// lane, only LDS dest is wave-base + lane*16).  32 K-iterations, 8 GLDS +
// 2 barriers + 32 MFMA each — doubles MFMA-per-barrier-drain vs R4.
// LDS 32 KB -> still 4 blocks/CU (reg-capped), below m132's 64 KB cliff.
// Grid (64,8,2) = 1024 blocks.  Partials bf16 to P + z*MM*OUT_DIM.
// Fragment layouts (HW-verified, learn_hip m89):
//   A/B operand: outer = lane&15, k = (lane>>4)*8 + j
//   C/D:         col   = lane&15, row = (lane>>4)*4 + reg
// ---------------------------------------------------------------------------
#define TM 128
#define TN 128
#define BK 64
#define KSPLIT (IN_DIM / 2)

__global__ __launch_bounds__(256, 4) void k_gemm(const ushort* __restrict__ A,
                                                 const ushort* __restrict__ B,
                                                 ushort* __restrict__ P) {
    __shared__ __align__(16) ushort As[2][TM * 32];   // 2 x 8 KB
    __shared__ __align__(16) ushort Bs[2][TN * 32];   // 2 x 8 KB
    const int tid  = threadIdx.x;
    const int lane = tid & 63;
    const int wave = tid >> 6;
    const int wm   = (wave >> 1) * 64;
    const int wn   = (wave & 1) * 64;
    const int bm   = blockIdx.x * TM;
    const int bn   = blockIdx.y * TN;
    const int kb   = blockIdx.z * KSPLIT;
    const int quad = lane >> 4;
    const int lrow = lane & 15;

    // staging: wave w stages rows [w*32, w*32+32), 4 lanes per row (32 elems)
    const int srow  = wave * 32 + (lane >> 2);
    const int skoff = (lane & 3) * 8;
    const ushort* gA = A + (size_t)(bm + srow) * IN_DIM + kb + skoff;
    const ushort* gB = B + (size_t)(bn + srow) * IN_DIM + kb + skoff;
    const int lbase = wave * 1024;   // elements; chunk1 at +512

    fx4 acc[4][4] = {};

    for (int k0 = 0; k0 < KSPLIT; k0 += BK) {
#pragma unroll
        for (int h = 0; h < 2; ++h) {
            GLDS(gA + k0 + h * 32,                As[h] + lbase);
            GLDS(gA + k0 + h * 32 + 16 * IN_DIM,  As[h] + lbase + 512);
            GLDS(gB + k0 + h * 32,                Bs[h] + lbase);
            GLDS(gB + k0 + h * 32 + 16 * IN_DIM,  Bs[h] + lbase + 512);
        }
        __syncthreads();

#pragma unroll
        for (int h = 0; h < 2; ++h) {
            bf16x8 af[4], bfr[4];
#pragma unroll
            for (int mi = 0; mi < 4; ++mi)
                af[mi] = *reinterpret_cast<const bf16x8*>(As[h] + (wm + mi * 16 + lrow) * 32 + quad * 8);
#pragma unroll
            for (int ni = 0; ni < 4; ++ni)
                bfr[ni] = *reinterpret_cast<const bf16x8*>(Bs[h] + (wn + ni * 16 + lrow) * 32 + quad * 8);
#pragma unroll
            for (int mi = 0; mi < 4; ++mi)
#pragma unroll
                for (int ni = 0; ni < 4; ++ni)
                    acc[mi][ni] = __builtin_amdgcn_mfma_f32_16x16x32_bf16(af[mi], bfr[ni], acc[mi][ni], 0, 0, 0);
        }
        __syncthreads();
    }

    ushort* Pz = P + (size_t)blockIdx.z * MM * OUT_DIM;
#pragma unroll
    for (int mi = 0; mi < 4; ++mi)
#pragma unroll
        for (int ni = 0; ni < 4; ++ni) {
            int r = bm + wm + mi * 16 + quad * 4;
            int c = bn + wn + ni * 16 + lrow;
#pragma unroll
            for (int v = 0; v < 4; ++v)
                Pz[(size_t)(r + v) * OUT_DIM + c] = f2bf(acc[mi][ni][v]);
        }
}

// ---------------------------------------------------------------------------
// K6: parallel prologue — lanes 0..15 of wave 0: load idx/beta, shfl-dedupe
// (dup -> weight 0 == reference set semantics), shfl softmax.  Then all 256
// threads gather: out = sum_t w_t * (P0[j_t] + P1[j_t]).
// ---------------------------------------------------------------------------
__global__ __launch_bounds__(256) void k_aggregate(const ushort* __restrict__ P,
                                                   const float* __restrict__ nalpha,
                                                   const float* __restrict__ nbeta,
                                                   const int* __restrict__ nidx,
                                                   float* __restrict__ outp) {
    int row = blockIdx.x;
    __shared__ int   s_idx[NSAMP];
    __shared__ float s_w[NSAMP];
    if (threadIdx.x < 16) {
        int t = threadIdx.x;
        int j = (t < NSAMP) ? nidx[row * NSAMP + t] : -1;
        float score = -INFINITY;
        if (t < NSAMP) {
            float x = nalpha[row] + nbeta[j];
            score = x > 0.f ? x : 0.2f * x;
        }
        bool dup = false;
#pragma unroll
        for (int sIdx = 0; sIdx < NSAMP; ++sIdx) {
            int js = __shfl(j, sIdx, 16);
            if (sIdx < t && js == j) dup = true;
        }
        float mx = score;
#pragma unroll
        for (int off = 8; off > 0; off >>= 1) {
            float o = __shfl_xor(mx, off, 16);
            mx = o > mx ? o : mx;
        }
        float e = (t < NSAMP && !dup) ? expf(score - mx) : 0.f;
        float sum = e;
#pragma unroll
        for (int off = 8; off > 0; off >>= 1) sum += __shfl_xor(sum, off, 16);
        if (t < NSAMP) {
            s_idx[t] = j;
            s_w[t]   = e / sum;
        }
    }
    __syncthreads();
    int col = threadIdx.x * 4;
    float ax = 0.f, ay = 0.f, az = 0.f, aw = 0.f;
#pragma unroll
    for (int t = 0; t < NSAMP; ++t) {
        float w = s_w[t];
        size_t off = (size_t)s_idx[t] * OUT_DIM + col;
        ushort4 u0 = *reinterpret_cast<const ushort4*>(P + off);
        ushort4 u1 = *reinterpret_cast<const ushort4*>(P + (size_t)MM * OUT_DIM + off);
        ax += w * (bf2f(u0.x) + bf2f(u1.x));
        ay += w * (bf2f(u0.y) + bf2f(u1.y));
        az += w * (bf2f(u0.z) + bf2f(u1.z));
        aw += w * (bf2f(u0.w) + bf2f(u1.w));
    }
    float4 o; o.x = ax; o.y = ay; o.z = az; o.w = aw;
    *reinterpret_cast<float4*>(outp + (size_t)row * OUT_DIM + col) = o;
}

// ---------------------------------------------------------------------------
extern "C" void kernel_launch(void* const* d_in, const int* in_sizes, int n_in,
                              void* d_out, int out_size, void* d_ws, size_t ws_size,
                              hipStream_t stream) {
    const float* node_f  = (const float*)d_in[0];  // 4096 x 4096
    const float* neigh_f = (const float*)d_in[1];  // 8192 x 4096
    const float* W       = (const float*)d_in[2];  // 1024 x 4096
    const float* att     = (const float*)d_in[3];  // 2048
    const int*   nidx    = (const int*)d_in[4];    // 4096 x 10
    float* outp = (float*)d_out;                   // 4096 x 1024 fp32

    char* ws = (char*)d_ws;
    ushort* Abf = (ushort*)ws;                     // 64 MB bf16 A
    ushort* Wbf = (ushort*)(ws + 67108864);        // 8 MB  bf16 W
    ushort* P   = (ushort*)(ws + 75497472);        // 2 x 16 MB bf16 partials
    float*  v1     = (float*)(ws + 109051904);
    float*  v2     = v1 + IN_DIM;
    float*  nalpha = v2 + IN_DIM;
    float*  nbeta  = nalpha + NN;

    hipMemsetAsync(v1, 0, 2 * IN_DIM * sizeof(float), stream);

    k_attvec   <<<dim3(4, 64),  256, 0, stream>>>(W, att, v1, v2, Wbf);
    k_rows     <<<NN + MM,      256, 0, stream>>>(node_f, neigh_f, v1, v2, nalpha, nbeta, Abf);
    k_gemm     <<<dim3(MM / TM, OUT_DIM / TN, 2), 256, 0, stream>>>(Abf, Wbf, P);
    k_aggregate<<<NN,           256, 0, stream>>>(P, nalpha, nbeta, nidx, outp);
}